// Round 1
// baseline (1485.261 us; speedup 1.0000x reference)
//
#include <hip/hip_runtime.h>
#include <math.h>

#define EMBED 1024
#define NHEAD 16
#define HDIM  64
#define BATCH 2
#define SEQ   2048
#define MROWS (BATCH*SEQ)

// C[m][n] = (sum_k A[m][k]*W[n][k] + bias[n]) * scale
// A: [M][K] row-major, W: [N][K] row-major (torch Linear weight layout).
// HEADSPLIT=1: write C into [(b*NHEAD+h)*SEQ+s][HDIM] head-split layout.
template<int HEADSPLIT>
__global__ __launch_bounds__(256)
void gemm_nt(const float* __restrict__ A,
             const float* __restrict__ W,
             const float* __restrict__ bias,
             float* __restrict__ C,
             int M, int N, int K, float scale)
{
    __shared__ float As[16][132];   // [k][m] transposed tile, pad 132 (mult of 4)
    __shared__ float Bs[16][132];   // [k][n]
    const int tid = threadIdx.x;
    const int tx = tid & 15;
    const int ty = tid >> 4;
    const int m0 = blockIdx.y << 7;
    const int n0 = blockIdx.x << 7;
    const int lr = tid >> 2;          // 0..63
    const int lc = (tid & 3) << 2;    // 0,4,8,12

    float acc[2][2][4][4];
    #pragma unroll
    for (int a = 0; a < 2; ++a)
      #pragma unroll
      for (int b = 0; b < 2; ++b)
        #pragma unroll
        for (int i = 0; i < 4; ++i)
          #pragma unroll
          for (int j = 0; j < 4; ++j) acc[a][b][i][j] = 0.f;

    const float* pa0 = A + (size_t)(m0 + lr) * K + lc;
    const float* pa1 = A + (size_t)(m0 + 64 + lr) * K + lc;
    const float* pw0 = W + (size_t)(n0 + lr) * K + lc;
    const float* pw1 = W + (size_t)(n0 + 64 + lr) * K + lc;

    for (int k0 = 0; k0 < K; k0 += 16) {
        float4 a0 = *(const float4*)(pa0 + k0);
        float4 a1 = *(const float4*)(pa1 + k0);
        float4 w0 = *(const float4*)(pw0 + k0);
        float4 w1 = *(const float4*)(pw1 + k0);
        __syncthreads();   // previous iteration's reads done
        As[lc+0][lr] = a0.x; As[lc+1][lr] = a0.y; As[lc+2][lr] = a0.z; As[lc+3][lr] = a0.w;
        As[lc+0][64+lr] = a1.x; As[lc+1][64+lr] = a1.y; As[lc+2][64+lr] = a1.z; As[lc+3][64+lr] = a1.w;
        Bs[lc+0][lr] = w0.x; Bs[lc+1][lr] = w0.y; Bs[lc+2][lr] = w0.z; Bs[lc+3][lr] = w0.w;
        Bs[lc+0][64+lr] = w1.x; Bs[lc+1][64+lr] = w1.y; Bs[lc+2][64+lr] = w1.z; Bs[lc+3][64+lr] = w1.w;
        __syncthreads();
        #pragma unroll
        for (int c = 0; c < 16; ++c) {
            float4 xA = *(const float4*)&As[c][ty<<2];
            float4 xB = *(const float4*)&As[c][64+(ty<<2)];
            float4 yA = *(const float4*)&Bs[c][tx<<2];
            float4 yB = *(const float4*)&Bs[c][64+(tx<<2)];
            float av[2][4] = {{xA.x,xA.y,xA.z,xA.w},{xB.x,xB.y,xB.z,xB.w}};
            float bv[2][4] = {{yA.x,yA.y,yA.z,yA.w},{yB.x,yB.y,yB.z,yB.w}};
            #pragma unroll
            for (int ri = 0; ri < 2; ++ri)
              #pragma unroll
              for (int cj = 0; cj < 2; ++cj)
                #pragma unroll
                for (int i = 0; i < 4; ++i)
                  #pragma unroll
                  for (int j = 0; j < 4; ++j)
                    acc[ri][cj][i][j] += av[ri][i] * bv[cj][j];
        }
    }

    #pragma unroll
    for (int ri = 0; ri < 2; ++ri) {
      #pragma unroll
      for (int i = 0; i < 4; ++i) {
        const int row = m0 + (ri<<6) + (ty<<2) + i;
        #pragma unroll
        for (int cj = 0; cj < 2; ++cj) {
            const int col = n0 + (cj<<6) + (tx<<2);
            const float4 bb = *(const float4*)&bias[col];
            float4 v;
            v.x = (acc[ri][cj][i][0] + bb.x) * scale;
            v.y = (acc[ri][cj][i][1] + bb.y) * scale;
            v.z = (acc[ri][cj][i][2] + bb.z) * scale;
            v.w = (acc[ri][cj][i][3] + bb.w) * scale;
            if (HEADSPLIT) {
                const int b_ = row >> 11;           // row / SEQ
                const int s_ = row & (SEQ-1);
                const int h_ = col >> 6;            // col / HDIM
                const int dh = col & (HDIM-1);
                *(float4*)&C[((size_t)(b_*NHEAD + h_)*SEQ + s_)*HDIM + dh] = v;
            } else {
                *(float4*)&C[(size_t)row*N + col] = v;
            }
        }
      }
    }
}

// Flash attention, fp32. One block per (b, h, 64 q-rows).
// Q/K/V in [B*H][SEQ][HDIM] layout (Q pre-scaled by 1/8).
__global__ __launch_bounds__(256, 2)
void attn_kernel(const float* __restrict__ Qw,
                 const float* __restrict__ Kw,
                 const float* __restrict__ Vw,
                 const float* __restrict__ bias,
                 float* __restrict__ ctx)
{
    __shared__ float Qs[64][68];   // [d][q] transposed
    __shared__ float Ks[64][68];   // [d][k] transposed
    __shared__ float Vs[64][68];   // [k][d] row-major
    __shared__ float Ps[64][68];   // [k][q] transposed
    __shared__ float mS[64];
    __shared__ float lS[64];

    const int tid = threadIdx.x;
    const int tx = tid & 15;
    const int ty = tid >> 4;
    const int q0 = blockIdx.x << 6;
    const int yy = blockIdx.y;
    const int h  = yy >> 1;          // b=0/1 adjacent for the same h => bias rows L2-shared
    const int b  = yy & 1;
    const int bh = b * NHEAD + h;

    const float* qp = Qw + (size_t)bh * SEQ * HDIM;
    const float* kp = Kw + (size_t)bh * SEQ * HDIM;
    const float* vp = Vw + (size_t)bh * SEQ * HDIM;
    const float* bp = bias + (size_t)h * SEQ * SEQ;

    const int lr = tid >> 2;          // 0..63
    const int lc = (tid & 3) << 2;    // 0,4,8,12

    // stage Q (transposed to [d][q])
    #pragma unroll
    for (int qq = 0; qq < 4; ++qq) {
        const int c = lc + (qq << 4);
        float4 v4 = *(const float4*)&qp[(size_t)(q0 + lr) * HDIM + c];
        Qs[c+0][lr] = v4.x; Qs[c+1][lr] = v4.y; Qs[c+2][lr] = v4.z; Qs[c+3][lr] = v4.w;
    }
    if (tid < 64) { mS[tid] = -INFINITY; lS[tid] = 0.f; }

    float o[4][4] = {};
    __syncthreads();

    for (int k0 = 0; k0 < SEQ; k0 += 64) {
        // fetch K/V tile to regs first (hide under previous tile's PV)
        float4 kreg[4], vreg[4];
        #pragma unroll
        for (int qq = 0; qq < 4; ++qq) {
            const int c = lc + (qq << 4);
            kreg[qq] = *(const float4*)&kp[(size_t)(k0 + lr) * HDIM + c];
            vreg[qq] = *(const float4*)&vp[(size_t)(k0 + lr) * HDIM + c];
        }
        __syncthreads();   // previous PV / scores done with Ks,Vs
        #pragma unroll
        for (int qq = 0; qq < 4; ++qq) {
            const int c = lc + (qq << 4);
            Ks[c+0][lr] = kreg[qq].x; Ks[c+1][lr] = kreg[qq].y;
            Ks[c+2][lr] = kreg[qq].z; Ks[c+3][lr] = kreg[qq].w;
            *(float4*)&Vs[lr][c] = vreg[qq];
        }
        __syncthreads();

        // scores: s[i][j] = q(row ty*4+i) . k(col tx*4+j)   (Q pre-scaled)
        float s[4][4] = {};
        #pragma unroll 8
        for (int d = 0; d < 64; ++d) {
            float4 qa = *(const float4*)&Qs[d][ty<<2];
            float4 ka = *(const float4*)&Ks[d][tx<<2];
            float qv[4] = {qa.x,qa.y,qa.z,qa.w};
            float kv[4] = {ka.x,ka.y,ka.z,ka.w};
            #pragma unroll
            for (int i = 0; i < 4; ++i)
              #pragma unroll
              for (int j = 0; j < 4; ++j)
                s[i][j] += qv[i] * kv[j];
        }

        // bias + online softmax (row = q, 16 tx-lanes per row, same wave)
        #pragma unroll
        for (int i = 0; i < 4; ++i) {
            const int q = (ty<<2) + i;
            const float4 bb = *(const float4*)&bp[(size_t)(q0+q)*SEQ + k0 + (tx<<2)];
            s[i][0] += bb.x; s[i][1] += bb.y; s[i][2] += bb.z; s[i][3] += bb.w;

            float tmax = fmaxf(fmaxf(s[i][0], s[i][1]), fmaxf(s[i][2], s[i][3]));
            tmax = fmaxf(tmax, __shfl_xor(tmax, 1));
            tmax = fmaxf(tmax, __shfl_xor(tmax, 2));
            tmax = fmaxf(tmax, __shfl_xor(tmax, 4));
            tmax = fmaxf(tmax, __shfl_xor(tmax, 8));

            const float m_old = mS[q];
            const float m_new = fmaxf(m_old, tmax);
            const float p0 = __expf(s[i][0] - m_new);
            const float p1 = __expf(s[i][1] - m_new);
            const float p2 = __expf(s[i][2] - m_new);
            const float p3 = __expf(s[i][3] - m_new);
            float psum = p0 + p1 + p2 + p3;
            psum += __shfl_xor(psum, 1);
            psum += __shfl_xor(psum, 2);
            psum += __shfl_xor(psum, 4);
            psum += __shfl_xor(psum, 8);

            const float scl = __expf(m_old - m_new);   // exp(-inf)=0 on first tile
            o[i][0] *= scl; o[i][1] *= scl; o[i][2] *= scl; o[i][3] *= scl;
            if (tx == 0) { mS[q] = m_new; lS[q] = lS[q] * scl + psum; }

            const int kk = tx << 2;
            Ps[kk+0][q] = p0; Ps[kk+1][q] = p1; Ps[kk+2][q] = p2; Ps[kk+3][q] = p3;
        }
        __syncthreads();

        // PV: o[i][j] += sum_k P[q][k] * V[k][d]
        #pragma unroll 8
        for (int k = 0; k < 64; ++k) {
            float4 pa = *(const float4*)&Ps[k][ty<<2];
            float4 va = *(const float4*)&Vs[k][tx<<2];
            float pv[4] = {pa.x,pa.y,pa.z,pa.w};
            float vv[4] = {va.x,va.y,va.z,va.w};
            #pragma unroll
            for (int i = 0; i < 4; ++i)
              #pragma unroll
              for (int j = 0; j < 4; ++j)
                o[i][j] += pv[i] * vv[j];
        }
    }
    __syncthreads();

    // finalize: divide by l, write ctx in [B][S][H*HDIM] layout
    #pragma unroll
    for (int i = 0; i < 4; ++i) {
        const int q = (ty<<2) + i;
        const float linv = 1.0f / lS[q];
        float4 v;
        v.x = o[i][0]*linv; v.y = o[i][1]*linv; v.z = o[i][2]*linv; v.w = o[i][3]*linv;
        *(float4*)&ctx[(size_t)(b*SEQ + q0 + q)*EMBED + h*HDIM + (tx<<2)] = v;
    }
}

extern "C" void kernel_launch(void* const* d_in, const int* in_sizes, int n_in,
                              void* d_out, int out_size, void* d_ws, size_t ws_size,
                              hipStream_t stream)
{
    const float* hs   = (const float*)d_in[0];
    const float* bias = (const float*)d_in[1];
    const float* Wq   = (const float*)d_in[2];
    const float* bq   = (const float*)d_in[3];
    const float* Wk   = (const float*)d_in[4];
    const float* bk   = (const float*)d_in[5];
    const float* Wv   = (const float*)d_in[6];
    const float* bv   = (const float*)d_in[7];
    const float* Wo   = (const float*)d_in[8];
    const float* bo   = (const float*)d_in[9];
    float* out = (float*)d_out;

    float* qws = (float*)d_ws;                      // [B*H][S][HDIM]
    float* kws = qws + (size_t)MROWS * EMBED;
    float* vws = kws + (size_t)MROWS * EMBED;
    float* cws = vws + (size_t)MROWS * EMBED;       // ctx [B][S][EMBED]

    dim3 blk(256);
    dim3 gg(EMBED/128, MROWS/128);                  // (8, 32)

    gemm_nt<1><<<gg, blk, 0, stream>>>(hs, Wq, bq, qws, MROWS, EMBED, EMBED, 0.125f);
    gemm_nt<1><<<gg, blk, 0, stream>>>(hs, Wk, bk, kws, MROWS, EMBED, EMBED, 1.0f);
    gemm_nt<1><<<gg, blk, 0, stream>>>(hs, Wv, bv, vws, MROWS, EMBED, EMBED, 1.0f);

    attn_kernel<<<dim3(SEQ/64, BATCH*NHEAD), blk, 0, stream>>>(qws, kws, vws, bias, cws);

    gemm_nt<0><<<gg, blk, 0, stream>>>(cws, Wo, bo, out, MROWS, EMBED, EMBED, 1.0f);
}

// Round 2
// 628.026 us; speedup vs baseline: 2.3650x; 2.3650x over previous
//
#include <hip/hip_runtime.h>
#include <math.h>

#define EMBED 1024
#define NHEAD 16
#define HDIM  64
#define BATCH 2
#define SEQ   2048
#define MROWS (BATCH*SEQ)

typedef __bf16 bf16x8 __attribute__((ext_vector_type(8)));
typedef __bf16 bf16x4 __attribute__((ext_vector_type(4)));
typedef __bf16 bf16x2 __attribute__((ext_vector_type(2)));
typedef float  f32x4  __attribute__((ext_vector_type(4)));

__device__ __forceinline__ f32x4 mfma16(bf16x8 a, bf16x8 b, f32x4 c) {
    return __builtin_amdgcn_mfma_f32_16x16x32_bf16(a, b, c, 0, 0, 0);
}

// ---------------- cast fp32 -> bf16 ----------------
__global__ __launch_bounds__(256)
void cast_kernel(const float* __restrict__ s, __bf16* __restrict__ d, int n4)
{
    const int i = blockIdx.x * 256 + threadIdx.x;
    if (i < n4) {
        const float4 v = ((const float4*)s)[i];
        bf16x4 o;
        o[0] = (__bf16)v.x; o[1] = (__bf16)v.y; o[2] = (__bf16)v.z; o[3] = (__bf16)v.w;
        ((bf16x4*)d)[i] = o;
    }
}

// ---------------- fused QKV projection (bf16 MFMA) ----------------
// C[m][n] = sum_k A[m][k]*W[n][k]; n-space is [Wq | Wk | Wv] (3*1024).
// Output head-split bf16 [B*H][SEQ][HDIM]; q pre-scaled by 0.125.
__global__ __launch_bounds__(256)
void gemm_qkv(const __bf16* __restrict__ A,
              const __bf16* __restrict__ W0, const __bf16* __restrict__ W1, const __bf16* __restrict__ W2,
              const float* __restrict__ b0, const float* __restrict__ b1, const float* __restrict__ b2,
              __bf16* __restrict__ dq, __bf16* __restrict__ dk, __bf16* __restrict__ dv)
{
    __shared__ __bf16 As[128][40];
    __shared__ __bf16 Bs[128][40];
    const int tid = threadIdx.x;
    const int m0  = blockIdx.y << 7;
    const int ngl = blockIdx.x << 7;
    const int which = ngl >> 10;
    const int n0  = ngl & 1023;
    const __bf16* W   = (which == 0) ? W0 : (which == 1) ? W1 : W2;
    const float* bias = (which == 0) ? b0 : (which == 1) ? b1 : b2;
    __bf16* dst       = (which == 0) ? dq : (which == 1) ? dk : dv;
    const float scale = (which == 0) ? 0.125f : 1.0f;

    const int wid = tid >> 6, lane = tid & 63;
    const int wm = wid >> 1, wn = wid & 1;
    const int lg = lane >> 4, lr = lane & 15;
    const int sr = tid >> 1;              // 0..127
    const int sc = (tid & 1) << 4;        // 0 / 16

    const __bf16* pa = A + (size_t)(m0 + sr) * EMBED + sc;
    const __bf16* pw = W + (size_t)(n0 + sr) * EMBED + sc;

    const f32x4 z4 = {0.f, 0.f, 0.f, 0.f};
    f32x4 acc[4][4];
    #pragma unroll
    for (int i = 0; i < 4; ++i)
        #pragma unroll
        for (int j = 0; j < 4; ++j) acc[i][j] = z4;

    for (int k0 = 0; k0 < EMBED; k0 += 32) {
        const bf16x8 a0 = *(const bf16x8*)(pa + k0);
        const bf16x8 a1 = *(const bf16x8*)(pa + k0 + 8);
        const bf16x8 w0 = *(const bf16x8*)(pw + k0);
        const bf16x8 w1 = *(const bf16x8*)(pw + k0 + 8);
        __syncthreads();
        *(bf16x8*)&As[sr][sc]     = a0;
        *(bf16x8*)&As[sr][sc + 8] = a1;
        *(bf16x8*)&Bs[sr][sc]     = w0;
        *(bf16x8*)&Bs[sr][sc + 8] = w1;
        __syncthreads();
        bf16x8 af[4], bfr[4];
        #pragma unroll
        for (int mf = 0; mf < 4; ++mf) af[mf]  = *(const bf16x8*)&As[(wm << 6) + (mf << 4) + lr][lg << 3];
        #pragma unroll
        for (int nf = 0; nf < 4; ++nf) bfr[nf] = *(const bf16x8*)&Bs[(wn << 6) + (nf << 4) + lr][lg << 3];
        #pragma unroll
        for (int mf = 0; mf < 4; ++mf)
            #pragma unroll
            for (int nf = 0; nf < 4; ++nf)
                acc[mf][nf] = mfma16(af[mf], bfr[nf], acc[mf][nf]);
    }

    #pragma unroll
    for (int nf = 0; nf < 4; ++nf) {
        const int cW = n0 + (wn << 6) + (nf << 4) + lr;   // col within this W
        const float bb = bias[cW];
        const int hh = cW >> 6, dh = cW & 63;
        #pragma unroll
        for (int mf = 0; mf < 4; ++mf) {
            #pragma unroll
            for (int reg = 0; reg < 4; ++reg) {
                const int row = m0 + (wm << 6) + (mf << 4) + (lg << 2) + reg;
                const int b_ = row >> 11, s_ = row & (SEQ - 1);
                const float v = (acc[mf][nf][reg] + bb) * scale;
                dst[((size_t)(b_ * NHEAD + hh) * SEQ + s_) * HDIM + dh] = (__bf16)v;
            }
        }
    }
}

// ---------------- output projection (bf16 MFMA, fp32 out) ----------------
__global__ __launch_bounds__(256)
void gemm_out(const __bf16* __restrict__ A, const __bf16* __restrict__ W,
              const float* __restrict__ bias, float* __restrict__ C)
{
    __shared__ __bf16 As[128][40];
    __shared__ __bf16 Bs[128][40];
    const int tid = threadIdx.x;
    const int m0 = blockIdx.y << 7;
    const int n0 = blockIdx.x << 7;
    const int wid = tid >> 6, lane = tid & 63;
    const int wm = wid >> 1, wn = wid & 1;
    const int lg = lane >> 4, lr = lane & 15;
    const int sr = tid >> 1;
    const int sc = (tid & 1) << 4;

    const __bf16* pa = A + (size_t)(m0 + sr) * EMBED + sc;
    const __bf16* pw = W + (size_t)(n0 + sr) * EMBED + sc;

    const f32x4 z4 = {0.f, 0.f, 0.f, 0.f};
    f32x4 acc[4][4];
    #pragma unroll
    for (int i = 0; i < 4; ++i)
        #pragma unroll
        for (int j = 0; j < 4; ++j) acc[i][j] = z4;

    for (int k0 = 0; k0 < EMBED; k0 += 32) {
        const bf16x8 a0 = *(const bf16x8*)(pa + k0);
        const bf16x8 a1 = *(const bf16x8*)(pa + k0 + 8);
        const bf16x8 w0 = *(const bf16x8*)(pw + k0);
        const bf16x8 w1 = *(const bf16x8*)(pw + k0 + 8);
        __syncthreads();
        *(bf16x8*)&As[sr][sc]     = a0;
        *(bf16x8*)&As[sr][sc + 8] = a1;
        *(bf16x8*)&Bs[sr][sc]     = w0;
        *(bf16x8*)&Bs[sr][sc + 8] = w1;
        __syncthreads();
        bf16x8 af[4], bfr[4];
        #pragma unroll
        for (int mf = 0; mf < 4; ++mf) af[mf]  = *(const bf16x8*)&As[(wm << 6) + (mf << 4) + lr][lg << 3];
        #pragma unroll
        for (int nf = 0; nf < 4; ++nf) bfr[nf] = *(const bf16x8*)&Bs[(wn << 6) + (nf << 4) + lr][lg << 3];
        #pragma unroll
        for (int mf = 0; mf < 4; ++mf)
            #pragma unroll
            for (int nf = 0; nf < 4; ++nf)
                acc[mf][nf] = mfma16(af[mf], bfr[nf], acc[mf][nf]);
    }

    #pragma unroll
    for (int nf = 0; nf < 4; ++nf) {
        const int col = n0 + (wn << 6) + (nf << 4) + lr;
        const float bb = bias[col];
        #pragma unroll
        for (int mf = 0; mf < 4; ++mf) {
            #pragma unroll
            for (int reg = 0; reg < 4; ++reg) {
                const int row = m0 + (wm << 6) + (mf << 4) + (lg << 2) + reg;
                C[(size_t)row * EMBED + col] = acc[mf][nf][reg] + bb;
            }
        }
    }
}

// ---------------- flash attention (bf16 MFMA, fp32 softmax) ----------------
// Block: 64 q-rows (wave w owns rows w*16..w*16+15), K-tiles of 64.
__global__ __launch_bounds__(256)
void attn_mfma(const __bf16* __restrict__ Qw, const __bf16* __restrict__ Kw,
               const __bf16* __restrict__ Vw, const float* __restrict__ bias,
               __bf16* __restrict__ ctx)
{
    __shared__ __bf16 Ks[64][72];     // [kv][d], pad 72 -> conflict-free b128 frag reads
    __shared__ __bf16 Vt[64][72];     // [d][kv]
    __shared__ __bf16 Ps[4][16][72];  // per-wave P tile [q][kv]

    const int tid = threadIdx.x, wid = tid >> 6, lane = tid & 63;
    const int lg = lane >> 4, lr = lane & 15;
    const int q0 = blockIdx.x << 6;
    const int h = blockIdx.y >> 1, b = blockIdx.y & 1, bh = b * NHEAD + h;

    const __bf16* qp = Qw + (size_t)bh * SEQ * HDIM;
    const __bf16* kp = Kw + (size_t)bh * SEQ * HDIM;
    const __bf16* vp = Vw + (size_t)bh * SEQ * HDIM;
    const float*  bp = bias + (size_t)h * SEQ * SEQ + (size_t)(q0 + (wid << 4)) * SEQ;

    // Q fragments live in registers for the whole block (Q pre-scaled by 1/8)
    const int qrow = q0 + (wid << 4) + lr;
    const bf16x8 qf0 = *(const bf16x8*)&qp[(size_t)qrow * HDIM + (lg << 3)];
    const bf16x8 qf1 = *(const bf16x8*)&qp[(size_t)qrow * HDIM + 32 + (lg << 3)];

    const f32x4 z4 = {0.f, 0.f, 0.f, 0.f};
    f32x4 O[4];
    O[0] = O[1] = O[2] = O[3] = z4;
    float m_r[4] = {-1e30f, -1e30f, -1e30f, -1e30f};
    float l_r[4] = {0.f, 0.f, 0.f, 0.f};

    // staging map: thread covers kv rows {kv0, kv0+1} x d [d0, d0+8)
    const int d0  = (tid & 7) << 3;       // 0..56
    const int kv0 = (tid >> 3) << 1;      // 0..62

    for (int k0 = 0; k0 < SEQ; k0 += 64) {
        const __bf16* kbase = kp + (size_t)(k0 + kv0) * HDIM + d0;
        const __bf16* vbase = vp + (size_t)(k0 + kv0) * HDIM + d0;
        const bf16x8 ka0 = *(const bf16x8*)kbase;
        const bf16x8 ka1 = *(const bf16x8*)(kbase + HDIM);
        const bf16x8 va0 = *(const bf16x8*)vbase;
        const bf16x8 va1 = *(const bf16x8*)(vbase + HDIM);
        __syncthreads();                       // everyone done reading Ks/Vt
        *(bf16x8*)&Ks[kv0][d0]     = ka0;
        *(bf16x8*)&Ks[kv0 + 1][d0] = ka1;
        #pragma unroll
        for (int j = 0; j < 8; ++j) {          // V transpose: paired bf16x2 writes
            bf16x2 pr; pr[0] = va0[j]; pr[1] = va1[j];
            *(bf16x2*)&Vt[d0 + j][kv0] = pr;
        }
        __syncthreads();

        // bias loads issued early (hide under QK^T MFMAs)
        float bv[4][4];
        #pragma unroll
        for (int nf = 0; nf < 4; ++nf)
            #pragma unroll
            for (int reg = 0; reg < 4; ++reg)
                bv[nf][reg] = bp[(size_t)((lg << 2) + reg) * SEQ + k0 + (nf << 4) + lr];

        // QK^T
        f32x4 S[4];
        S[0] = S[1] = S[2] = S[3] = z4;
        #pragma unroll
        for (int nf = 0; nf < 4; ++nf) {
            const bf16x8 kf0 = *(const bf16x8*)&Ks[(nf << 4) + lr][lg << 3];
            S[nf] = mfma16(qf0, kf0, S[nf]);
            const bf16x8 kf1 = *(const bf16x8*)&Ks[(nf << 4) + lr][32 + (lg << 3)];
            S[nf] = mfma16(qf1, kf1, S[nf]);
        }

        // online softmax: row q = lg*4+reg, cols = nf*16+lr
        float p[4][4], scl[4];
        #pragma unroll
        for (int reg = 0; reg < 4; ++reg) {
            const float s0 = S[0][reg] + bv[0][reg];
            const float s1 = S[1][reg] + bv[1][reg];
            const float s2 = S[2][reg] + bv[2][reg];
            const float s3 = S[3][reg] + bv[3][reg];
            float mx = fmaxf(fmaxf(s0, s1), fmaxf(s2, s3));
            mx = fmaxf(mx, __shfl_xor(mx, 1));
            mx = fmaxf(mx, __shfl_xor(mx, 2));
            mx = fmaxf(mx, __shfl_xor(mx, 4));
            mx = fmaxf(mx, __shfl_xor(mx, 8));
            const float mn = fmaxf(m_r[reg], mx);
            const float sc_ = __expf(m_r[reg] - mn);
            m_r[reg] = mn;
            scl[reg] = sc_;
            const float p0 = __expf(s0 - mn), p1 = __expf(s1 - mn);
            const float p2 = __expf(s2 - mn), p3 = __expf(s3 - mn);
            p[0][reg] = p0; p[1][reg] = p1; p[2][reg] = p2; p[3][reg] = p3;
            float ps = p0 + p1 + p2 + p3;
            ps += __shfl_xor(ps, 1);
            ps += __shfl_xor(ps, 2);
            ps += __shfl_xor(ps, 4);
            ps += __shfl_xor(ps, 8);
            l_r[reg] = l_r[reg] * sc_ + ps;
        }
        #pragma unroll
        for (int nf = 0; nf < 4; ++nf) {
            f32x4 o = O[nf];
            o[0] *= scl[0]; o[1] *= scl[1]; o[2] *= scl[2]; o[3] *= scl[3];
            O[nf] = o;
        }

        // P -> bf16 to wave-local LDS (nf rotated by lg: 2-way banks)
        #pragma unroll
        for (int nfx = 0; nfx < 4; ++nfx) {
            const int nf = (nfx + lg) & 3;
            #pragma unroll
            for (int reg = 0; reg < 4; ++reg)
                Ps[wid][(lg << 2) + reg][(nf << 4) + lr] = (__bf16)p[nf][reg];
        }
        asm volatile("s_waitcnt lgkmcnt(0)" ::: "memory");  // same-wave RAW on Ps

        // PV: O[q][d] += P[q][kv] * V[kv][d]
        #pragma unroll
        for (int s2 = 0; s2 < 2; ++s2) {
            const bf16x8 pf = *(const bf16x8*)&Ps[wid][lr][(s2 << 5) + (lg << 3)];
            #pragma unroll
            for (int nf = 0; nf < 4; ++nf) {
                const bf16x8 vf = *(const bf16x8*)&Vt[(nf << 4) + lr][(s2 << 5) + (lg << 3)];
                O[nf] = mfma16(pf, vf, O[nf]);
            }
        }
    }

    // epilogue: normalize and write ctx (bf16, [B][S][EMBED])
    #pragma unroll
    for (int nf = 0; nf < 4; ++nf) {
        #pragma unroll
        for (int reg = 0; reg < 4; ++reg) {
            const int q = q0 + (wid << 4) + (lg << 2) + reg;
            const float val = O[nf][reg] / l_r[reg];
            ctx[((size_t)(b * SEQ + q)) * EMBED + h * HDIM + (nf << 4) + lr] = (__bf16)val;
        }
    }
}

extern "C" void kernel_launch(void* const* d_in, const int* in_sizes, int n_in,
                              void* d_out, int out_size, void* d_ws, size_t ws_size,
                              hipStream_t stream)
{
    const float* hs   = (const float*)d_in[0];
    const float* bias = (const float*)d_in[1];
    const float* Wq   = (const float*)d_in[2];
    const float* bq   = (const float*)d_in[3];
    const float* Wk   = (const float*)d_in[4];
    const float* bk   = (const float*)d_in[5];
    const float* Wv   = (const float*)d_in[6];
    const float* bv   = (const float*)d_in[7];
    const float* Wo   = (const float*)d_in[8];
    const float* bo   = (const float*)d_in[9];
    float* out = (float*)d_out;

    __bf16* hsb = (__bf16*)d_ws;                      // 4096*1024
    __bf16* wqb = hsb + (size_t)MROWS * EMBED;
    __bf16* wkb = wqb + (size_t)EMBED * EMBED;
    __bf16* wvb = wkb + (size_t)EMBED * EMBED;
    __bf16* wob = wvb + (size_t)EMBED * EMBED;
    __bf16* qws = wob + (size_t)EMBED * EMBED;        // [32][2048][64]
    __bf16* kws = qws + (size_t)MROWS * EMBED;
    __bf16* vws = kws + (size_t)MROWS * EMBED;
    __bf16* cws = vws + (size_t)MROWS * EMBED;        // ctx bf16 [4096][1024]

    const int nHS = MROWS * EMBED / 4;                // 1048576
    const int nW  = EMBED * EMBED / 4;                // 262144
    cast_kernel<<<nHS / 256, 256, 0, stream>>>(hs, hsb, nHS);
    cast_kernel<<<nW / 256, 256, 0, stream>>>(Wq, wqb, nW);
    cast_kernel<<<nW / 256, 256, 0, stream>>>(Wk, wkb, nW);
    cast_kernel<<<nW / 256, 256, 0, stream>>>(Wv, wvb, nW);
    cast_kernel<<<nW / 256, 256, 0, stream>>>(Wo, wob, nW);

    gemm_qkv<<<dim3(24, 32), 256, 0, stream>>>(hsb, wqb, wkb, wvb, bq, bk, bv, qws, kws, vws);

    attn_mfma<<<dim3(SEQ / 64, BATCH * NHEAD), 256, 0, stream>>>(qws, kws, vws, bias, cws);

    gemm_out<<<dim3(8, 32), 256, 0, stream>>>(cws, wob, bo, out);
}